// Round 1
// 85.554 us; speedup vs baseline: 1.0123x; 1.0123x over previous
//
#include <hip/hip_runtime.h>
#include <math.h>

// Tropical (max-plus) matmul: y[b,o] = max_i (x[b,i] + W[o,i])
// x: [512,1024] f32, W: [1024,1024] f32 (both K-innermost), y: [512,1024] f32.
//
// VALU-issue-bound (no MFMA for max-plus, no fp32 MFMA on CDNA4).
// This version processes K in PAIRS so the inner op is
//   v_pk_add_f32 (2 adds) + v_max3_f32 (fold both sums into acc)
// = 1 VALU inst per output-element-k (was 2: v_add + v_max).
// LDS tiles are stored k-pair-interleaved As[k/2][m][k&1] so a ds_read_b128
// delivers register-adjacent (k0,k1) float2 pairs for two consecutive m.
//
// Split-K: 128 output tiles (64x64) x KS K-slices -> partial-max into
// workspace, then reduce. Exact (max associative; adds identical to ref).

#define MDIM 512
#define NDIM 1024
#define KDIM 1024

#define BM 64
#define BN 64
#define BK 32
#define KP (BK / 2)      // 16 pair-rows per tile
#define LDS_S 132        // floats per pair-row: BM*2 + 4 pad (16B-aligned stride, bank skew)
#define TM 4
#define TN 4
#define NTHREADS 256     // 16x16 thread grid, 4x4 outputs each

typedef float v2f __attribute__((ext_vector_type(2)));

__global__ __launch_bounds__(NTHREADS)
void tropical_partial(const float* __restrict__ x, const float* __restrict__ W,
                      float* __restrict__ ws, int KC) {
    __shared__ float As[KP][LDS_S];   // k-pair-interleaved: As[k/2][m*2 + (k&1)]
    __shared__ float Bs[KP][LDS_S];

    const int tiles_n = NDIM / BN;                 // 16
    const int tile    = blockIdx.x;                // 0..127
    const int tm0     = (tile / tiles_n) * BM;
    const int tn0     = (tile % tiles_n) * BN;
    const int k0      = blockIdx.y * KC;           // this block's K-slice

    const int tid = threadIdx.x;
    // staging map: each thread loads 8 consecutive k for one row (2x float4)
    const int sm = tid >> 2;          // 0..63  (row within tile)
    const int sk = (tid & 3) * 8;     // 0,8,16,24 (k offset)
    const int sp = sk >> 1;           // pair-row base: 0,4,8,12
    // compute map
    const int tx = tid & 15;          // n-direction
    const int ty = tid >> 4;          // m-direction

    float acc[TM][TN];
#pragma unroll
    for (int i = 0; i < TM; ++i)
#pragma unroll
        for (int j = 0; j < TN; ++j) acc[i][j] = -INFINITY;

    for (int kt = 0; kt < KC; kt += BK) {
        const int kb = k0 + kt;
        // global loads issued before the barrier (in flight during wait)
        const float4 a0 = *(const float4*)&x[(size_t)(tm0 + sm) * KDIM + kb + sk];
        const float4 a1 = *(const float4*)&x[(size_t)(tm0 + sm) * KDIM + kb + sk + 4];
        const float4 b0 = *(const float4*)&W[(size_t)(tn0 + sm) * KDIM + kb + sk];
        const float4 b1 = *(const float4*)&W[(size_t)(tn0 + sm) * KDIM + kb + sk + 4];

        __syncthreads();   // previous iter's frag reads done before overwrite
        // pair-interleaved stores: k-pair (2t,2t+1) of row sm -> one ds_write_b64
        {
            v2f t0; t0.x = a0.x; t0.y = a0.y;
            v2f t1; t1.x = a0.z; t1.y = a0.w;
            v2f t2; t2.x = a1.x; t2.y = a1.y;
            v2f t3; t3.x = a1.z; t3.y = a1.w;
            *(v2f*)&As[sp + 0][sm * 2] = t0;
            *(v2f*)&As[sp + 1][sm * 2] = t1;
            *(v2f*)&As[sp + 2][sm * 2] = t2;
            *(v2f*)&As[sp + 3][sm * 2] = t3;
            v2f u0; u0.x = b0.x; u0.y = b0.y;
            v2f u1; u1.x = b0.z; u1.y = b0.w;
            v2f u2; u2.x = b1.x; u2.y = b1.y;
            v2f u3; u3.x = b1.z; u3.y = b1.w;
            *(v2f*)&Bs[sp + 0][sm * 2] = u0;
            *(v2f*)&Bs[sp + 1][sm * 2] = u1;
            *(v2f*)&Bs[sp + 2][sm * 2] = u2;
            *(v2f*)&Bs[sp + 3][sm * 2] = u3;
        }
        __syncthreads();

#pragma unroll 8
        for (int kp = 0; kp < KP; ++kp) {
            // two float4 per operand: (k0,k1) pairs for 4 consecutive m / n
            const float4 aA = *(const float4*)&As[kp][ty * 8];
            const float4 aB = *(const float4*)&As[kp][ty * 8 + 4];
            const float4 bA = *(const float4*)&Bs[kp][tx * 8];
            const float4 bB = *(const float4*)&Bs[kp][tx * 8 + 4];
            v2f am[TM], bn[TN];
            am[0].x = aA.x; am[0].y = aA.y;
            am[1].x = aA.z; am[1].y = aA.w;
            am[2].x = aB.x; am[2].y = aB.y;
            am[3].x = aB.z; am[3].y = aB.w;
            bn[0].x = bA.x; bn[0].y = bA.y;
            bn[1].x = bA.z; bn[1].y = bA.w;
            bn[2].x = bB.x; bn[2].y = bB.y;
            bn[3].x = bB.z; bn[3].y = bB.w;
#pragma unroll
            for (int i = 0; i < TM; ++i)
#pragma unroll
                for (int j = 0; j < TN; ++j) {
                    const v2f s = am[i] + bn[j];               // v_pk_add_f32
                    acc[i][j] = fmaxf(fmaxf(acc[i][j], s.x), s.y);  // v_max3_f32
                }
        }
    }

    // write this K-slice's partial tile
    float* wsl = ws + (size_t)blockIdx.y * MDIM * NDIM;
#pragma unroll
    for (int i = 0; i < TM; ++i) {
        const float4 v = make_float4(acc[i][0], acc[i][1], acc[i][2], acc[i][3]);
        *(float4*)&wsl[(size_t)(tm0 + ty * TM + i) * NDIM + tn0 + tx * TN] = v;
    }
}

__global__ __launch_bounds__(NTHREADS)
void tropical_reduce(const float* __restrict__ ws, float* __restrict__ out, int KS) {
    const int i = blockIdx.x * NTHREADS + threadIdx.x;       // float4 index
    const int stride = MDIM * NDIM / 4;
    if (i >= stride) return;
    const float4* w4 = (const float4*)ws;
    float4 m = w4[i];
    for (int s = 1; s < KS; ++s) {
        const float4 v = w4[(size_t)s * stride + i];
        m.x = fmaxf(m.x, v.x); m.y = fmaxf(m.y, v.y);
        m.z = fmaxf(m.z, v.z); m.w = fmaxf(m.w, v.w);
    }
    ((float4*)out)[i] = m;
}

extern "C" void kernel_launch(void* const* d_in, const int* in_sizes, int n_in,
                              void* d_out, int out_size, void* d_ws, size_t ws_size,
                              hipStream_t stream) {
    const float* x = (const float*)d_in[0];
    const float* W = (const float*)d_in[1];
    float* out = (float*)d_out;
    float* ws  = (float*)d_ws;

    const size_t slice = (size_t)MDIM * NDIM * sizeof(float);  // 2 MB per K-slice
    int KS = 8;
    while (KS > 1 && (size_t)KS * slice > ws_size) KS >>= 1;

    const int ntiles = (MDIM / BM) * (NDIM / BN);  // 128

    if ((size_t)KS * slice > ws_size) {
        // tiny-workspace fallback: single slice straight into out, no reduce
        tropical_partial<<<dim3(ntiles, 1), NTHREADS, 0, stream>>>(x, W, out, KDIM);
        return;
    }

    const int KC = KDIM / KS;
    tropical_partial<<<dim3(ntiles, KS), NTHREADS, 0, stream>>>(x, W, ws, KC);

    const int nvec4 = MDIM * NDIM / 4;
    tropical_reduce<<<(nvec4 + NTHREADS - 1) / NTHREADS, NTHREADS, 0, stream>>>(ws, out, KS);
}